// Round 13
// baseline (190.801 us; speedup 1.0000x reference)
//
#include <hip/hip_runtime.h>
#include <math.h>

// Problem constants
#define NB   16
#define NN   512
#define FIN  256
#define HID  128
#define FOUT 256
#define TOPK 16
#define ROWS (NB*NN)
#define LN_EPS 1e-5f

#define BK   32
#define LDK  40     // padded LDS row (ushort): 80B stride
#define NTHR 256

typedef __attribute__((ext_vector_type(8)))  short  bf16x8;
typedef __attribute__((ext_vector_type(4)))  float  f32x4;
typedef __attribute__((ext_vector_type(8)))  unsigned short u16x8;

#define MFMA3(d, ah, al, bh, bl)                                              \
    d = __builtin_amdgcn_mfma_f32_16x16x32_bf16(ah, bh, d, 0, 0, 0);          \
    d = __builtin_amdgcn_mfma_f32_16x16x32_bf16(ah, bl, d, 0, 0, 0);          \
    d = __builtin_amdgcn_mfma_f32_16x16x32_bf16(al, bh, d, 0, 0, 0);

__device__ __forceinline__ ushort f2bf_rn(float x) {
    uint u = __float_as_uint(x);
    u += 0x7fff + ((u >> 16) & 1);
    return (ushort)(u >> 16);
}
__device__ __forceinline__ float bf2f(ushort h) {
    return __uint_as_float(((uint)h) << 16);
}
__device__ __forceinline__ void split2(float x, ushort& hi, ushort& lo) {
    hi = f2bf_rn(x);
    lo = f2bf_rn(x - bf2f(hi));
}

// stage 64 rows x 32 k from fp32 row-major source (contiguous k), split on fly
__device__ __forceinline__ void stage_rows64f(ushort (*Dh)[LDK], ushort (*Dl)[LDK],
                                              const float* __restrict__ src,
                                              int rstride, int tid)
{
    const int r = tid >> 2, seg = (tid & 3) * 8;
    const float* p = src + (size_t)r * rstride + seg;
    #pragma unroll
    for (int i = 0; i < 2; i++) {
        const float4 q = *(const float4*)(p + 4*i);
        ushort h0,l0,h1,l1,h2,l2,h3,l3;
        split2(q.x,h0,l0); split2(q.y,h1,l1);
        split2(q.z,h2,l2); split2(q.w,h3,l3);
        *(ushort4*)&Dh[r][seg + 4*i] = make_ushort4(h0,h1,h2,h3);
        *(ushort4*)&Dl[r][seg + 4*i] = make_ushort4(l0,l1,l2,l3);
    }
}

// stage transposed from fp32 [k][n] source (ld = ldn), write [n][k], n=64 wide
__device__ __forceinline__ void stage_cols64f(ushort (*Dh)[LDK], ushort (*Dl)[LDK],
                                              const float* __restrict__ src,
                                              int ldn, int tid)
{
    const int n = tid & 63, kh = (tid >> 6) * 8;
    const float* p = src + (size_t)kh * ldn + n;
    ushort hh[8], ll[8];
    #pragma unroll
    for (int i = 0; i < 8; i++) split2(p[(size_t)i * ldn], hh[i], ll[i]);
    *(ushort4*)&Dh[n][kh]     = make_ushort4(hh[0],hh[1],hh[2],hh[3]);
    *(ushort4*)&Dh[n][kh + 4] = make_ushort4(hh[4],hh[5],hh[6],hh[7]);
    *(ushort4*)&Dl[n][kh]     = make_ushort4(ll[0],ll[1],ll[2],ll[3]);
    *(ushort4*)&Dl[n][kh + 4] = make_ushort4(ll[4],ll[5],ll[6],ll[7]);
}

// stage 64 rows x 32 k of a pre-split ushort plane into LDS (pure copy)
__device__ __forceinline__ void stage_u(ushort (*Ds)[LDK], const ushort* __restrict__ src,
                                        int rstride, int tid)
{
    const int r = tid >> 2, seg = (tid & 3) * 8;
    *(u16x8*)&Ds[r][seg] = *(const u16x8*)(src + (size_t)r * rstride + seg);
}

__device__ __forceinline__ void mma_step64(const ushort (*Ah)[LDK], const ushort (*Al)[LDK],
                                           const ushort (*Bh)[LDK], const ushort (*Bl)[LDK],
                                           f32x4 acc[2][2], int wr, int wc, int lane)
{
    const int q8 = (lane >> 4) * 8, m = lane & 15;
    bf16x8 ah[2], al[2], bh[2], bl[2];
    #pragma unroll
    for (int i = 0; i < 2; i++) {
        ah[i] = *(const bf16x8*)&Ah[wr + 16*i + m][q8];
        al[i] = *(const bf16x8*)&Al[wr + 16*i + m][q8];
        bh[i] = *(const bf16x8*)&Bh[wc + 16*i + m][q8];
        bl[i] = *(const bf16x8*)&Bl[wc + 16*i + m][q8];
    }
    #pragma unroll
    for (int i = 0; i < 2; i++)
        #pragma unroll
        for (int j = 0; j < 2; j++) {
            MFMA3(acc[i][j], ah[i], al[i], bh[j], bl[j]);
        }
}

struct Params {
    const float *X, *Wq, *bq, *Wk, *bk, *Wv, *bv, *Wr, *br, *Wc, *bc, *lns, *lnb;
    float *out;
    float *Rbuf, *SQ, *AB, *D, *Opart, *Lpart;
    ushort *Yh, *Yl, *Vth, *Vtl, *Hh, *Hl, *Wcth, *Wctl;
};

// ===================== Phase A: projection (+ Wct prep in blocks >=1024) =====
__global__ __launch_bounds__(NTHR, 2) void k_pA(Params P)
{
    __shared__ ushort SMEM[4*64*LDK];

    const int tid = threadIdx.x;

    if (blockIdx.x >= 1024) {            // ---- Wct prep ----
        float (*fb)[65] = (float(*)[65])SMEM;
        const int n0 = (blockIdx.x - 1024) * 64;
        const bool ahalf = n0 < 256;
        const int cbase = n0 & 255;
        for (int kt = 0; kt < 2; kt++) {
            const int k0 = kt * 64;
            __syncthreads();
            {
                const int kk = tid >> 2, cs = (tid & 3) * 16;
                #pragma unroll
                for (int t = 0; t < 16; t++) {
                    const float bot = P.Wc[(size_t)(HID + k0 + kk)*FOUT + cbase + cs + t];
                    float val = bot;
                    if (ahalf) val = P.Wc[(size_t)(k0 + kk)*FOUT + cbase + cs + t] - bot;
                    fb[kk][cs+t] = val;
                }
            }
            __syncthreads();
            {
                const int c = tid >> 2, ks = (tid & 3) * 16;
                u16x8 vh0, vh1, vl0, vl1;
                #pragma unroll
                for (int t = 0; t < 8; t++) {
                    ushort hh, ll;
                    split2(fb[ks+t][c], hh, ll);   vh0[t]=hh; vl0[t]=ll;
                    split2(fb[ks+8+t][c], hh, ll); vh1[t]=hh; vl1[t]=ll;
                }
                *(u16x8*)&P.Wcth[(size_t)(n0+c)*128 + k0 + ks]     = vh0;
                *(u16x8*)&P.Wcth[(size_t)(n0+c)*128 + k0 + ks + 8] = vh1;
                *(u16x8*)&P.Wctl[(size_t)(n0+c)*128 + k0 + ks]     = vl0;
                *(u16x8*)&P.Wctl[(size_t)(n0+c)*128 + k0 + ks + 8] = vl1;
            }
        }
        return;
    }

    ushort (*Ah)[LDK] = (ushort(*)[LDK])(SMEM);
    ushort (*Al)[LDK] = (ushort(*)[LDK])(SMEM + 2560);
    ushort (*Bh)[LDK] = (ushort(*)[LDK])(SMEM + 5120);
    ushort (*Bl)[LDK] = (ushort(*)[LDK])(SMEM + 7680);
    float* fbuf = (float*)SMEM;

    const int lane = tid & 63, w = tid >> 6;
    const int wr = (w >> 1) * 32, wc = (w & 1) * 32;
    const int m = lane & 15, q4 = (lane >> 4) * 4;

    const int job = blockIdx.x;
    const int ct = job >> 7, br0 = (job & 127) * 64;
    const int widx = ct >> 1, ch = (ct & 1) * 64;
    const float* W    = widx==0 ? P.Wq : widx==1 ? P.Wk : widx==2 ? P.Wv : P.Wr;
    const float* bias = widx==0 ? P.bq : widx==1 ? P.bk : widx==2 ? P.bv : P.br;

    f32x4 acc[2][2];
    #pragma unroll
    for (int i = 0; i < 2; i++)
        #pragma unroll
        for (int j = 0; j < 2; j++) acc[i][j] = (f32x4){0.f,0.f,0.f,0.f};

    for (int k0 = 0; k0 < FIN; k0 += BK) {
        stage_rows64f(Ah, Al, P.X + (size_t)br0 * FIN + k0, FIN, tid);
        stage_cols64f(Bh, Bl, W + (size_t)k0 * HID + ch, HID, tid);
        __syncthreads();
        mma_step64(Ah, Al, Bh, Bl, acc, wr, wc, lane);
        __syncthreads();
    }
    #pragma unroll
    for (int i = 0; i < 2; i++)
        #pragma unroll
        for (int reg = 0; reg < 4; reg++) {
            const int r = wr + 16*i + q4 + reg;
            #pragma unroll
            for (int j = 0; j < 2; j++) {
                const int c = wc + 16*j + m;
                fbuf[r*65 + c] = acc[i][j][reg] + bias[ch + c];
            }
        }
    __syncthreads();

    if (ct < 4) {            // q|k planes, row-major [8192][256]; q pre-scaled
        const float qsc = (ct < 2) ? 0.08838834764831845f : 1.0f;
        const int r = tid >> 2, cs = (tid & 3) * 16;
        u16x8 vh0, vh1, vl0, vl1;
        #pragma unroll
        for (int t = 0; t < 8; t++) {
            ushort hh, ll;
            split2(fbuf[r*65 + cs + t] * qsc, hh, ll);     vh0[t]=hh; vl0[t]=ll;
            split2(fbuf[r*65 + cs + 8 + t] * qsc, hh, ll); vh1[t]=hh; vl1[t]=ll;
        }
        const size_t o = (size_t)(br0 + r) * 256 + ct*64 + cs;
        *(u16x8*)&P.Yh[o]   = vh0; *(u16x8*)&P.Yh[o+8] = vh1;
        *(u16x8*)&P.Yl[o]   = vl0; *(u16x8*)&P.Yl[o+8] = vl1;
    } else if (ct < 6) {     // V transposed planes [b][c=128][n=512]
        const int cl = tid >> 2, rs = (tid & 3) * 16;
        const int b = br0 >> 9, nb = br0 & 511;
        const int cglob = (ct - 4) * 64 + cl;
        u16x8 vh0, vh1, vl0, vl1;
        #pragma unroll
        for (int t = 0; t < 8; t++) {
            ushort hh, ll;
            split2(fbuf[(rs+t)*65 + cl], hh, ll);   vh0[t]=hh; vl0[t]=ll;
            split2(fbuf[(rs+8+t)*65 + cl], hh, ll); vh1[t]=hh; vl1[t]=ll;
        }
        const size_t o = ((size_t)b*128 + cglob) * 512 + nb + rs;
        *(u16x8*)&P.Vth[o]   = vh0; *(u16x8*)&P.Vth[o+8] = vh1;
        *(u16x8*)&P.Vtl[o]   = vl0; *(u16x8*)&P.Vtl[o+8] = vl1;
    } else {                 // R fp32 [8192][128]
        const int r = tid >> 2, cs = (tid & 3) * 16;
        float* dst = P.Rbuf + (size_t)(br0 + r) * 128 + (ct - 6)*64 + cs;
        #pragma unroll
        for (int t = 0; t < 16; t += 4) {
            float4 q;
            q.x = fbuf[r*65+cs+t];   q.y = fbuf[r*65+cs+t+1];
            q.z = fbuf[r*65+cs+t+2]; q.w = fbuf[r*65+cs+t+3];
            *(float4*)(dst + t) = q;
        }
    }
}

// ===================== Phase B: attention partials — barrier-free ============
// K and V fragments loaded directly from global (L2-resident); P buffers are
// wave-private LDS rows, so no __syncthreads anywhere in this kernel.
__global__ __launch_bounds__(NTHR, 2) void k_pB(Params P)
{
    __shared__ ushort SMEM[4*64*LDK];
    ushort (*P0h)[LDK] = (ushort(*)[LDK])(SMEM);
    ushort (*P0l)[LDK] = (ushort(*)[LDK])(SMEM + 2560);
    ushort (*P1h)[LDK] = (ushort(*)[LDK])(SMEM + 5120);
    ushort (*P1l)[LDK] = (ushort(*)[LDK])(SMEM + 7680);

    const int tid = threadIdx.x, lane = tid & 63, w = tid >> 6;
    const int L = lane & 15, quad = lane >> 4;

    const int job = blockIdx.x;
    const int b = job >> 6, rest = job & 63;
    const int n0 = (rest >> 3) * 64, mc = rest & 7, m0 = mc * 64;
    const int grow0 = b*NN + n0 + w*16;

    bf16x8 qh[4], ql[4];
    #pragma unroll
    for (int s = 0; s < 4; s++) {
        const size_t qo = (size_t)(grow0 + L) * 256 + s*32 + quad*8;
        qh[s] = *(const bf16x8*)(P.Yh + qo);
        ql[s] = *(const bf16x8*)(P.Yl + qo);
    }

    // S = q . k^T, K frags direct from global
    f32x4 Sf[4];
    #pragma unroll
    for (int j = 0; j < 4; j++) Sf[j] = (f32x4){0.f,0.f,0.f,0.f};
    #pragma unroll
    for (int s = 0; s < 4; s++)
        #pragma unroll
        for (int j = 0; j < 4; j++) {
            const size_t ko = (size_t)(b*NN + m0 + 16*j + L) * 256 + 128 + s*32 + quad*8;
            bf16x8 kh = *(const bf16x8*)(P.Yh + ko);
            bf16x8 kl = *(const bf16x8*)(P.Yl + ko);
            MFMA3(Sf[j], qh[s], ql[s], kh, kl);
        }

    // exp (no max shift: |s| small), stash P into wave-private LDS rows
    float ls[4] = {0.f, 0.f, 0.f, 0.f};
    #pragma unroll
    for (int j = 0; j < 4; j++)
        #pragma unroll
        for (int r = 0; r < 4; r++) {
            const float p = __expf(Sf[j][r]);
            ls[r] += p;
            const int row = w*16 + quad*4 + r, cc = (16*j + L) & 31;
            ushort hh, ll; split2(p, hh, ll);
            if (j < 2) { P0h[row][cc] = hh; P0l[row][cc] = ll; }
            else       { P1h[row][cc] = hh; P1l[row][cc] = ll; }
        }
    #pragma unroll
    for (int r = 0; r < 4; r++) {
        float v = ls[r];
        v += __shfl_xor(v, 1); v += __shfl_xor(v, 2);
        v += __shfl_xor(v, 4); v += __shfl_xor(v, 8);
        ls[r] = v;
    }

    // O = P @ V^T (V frags direct from global)
    f32x4 O[8];
    #pragma unroll
    for (int j = 0; j < 8; j++) O[j] = (f32x4){0.f,0.f,0.f,0.f};
    #pragma unroll
    for (int s2 = 0; s2 < 2; s2++) {
        bf16x8 ph = s2 ? *(const bf16x8*)&P1h[w*16 + L][quad*8]
                       : *(const bf16x8*)&P0h[w*16 + L][quad*8];
        bf16x8 pl = s2 ? *(const bf16x8*)&P1l[w*16 + L][quad*8]
                       : *(const bf16x8*)&P0l[w*16 + L][quad*8];
        #pragma unroll
        for (int j = 0; j < 8; j++) {
            const size_t vo = ((size_t)(b*128 + 16*j + L)) * 512 + m0 + s2*32 + quad*8;
            bf16x8 vh = *(const bf16x8*)(P.Vth + vo);
            bf16x8 vl = *(const bf16x8*)(P.Vtl + vo);
            MFMA3(O[j], ph, pl, vh, vl);
        }
    }

    #pragma unroll
    for (int j = 0; j < 8; j++)
        #pragma unroll
        for (int reg = 0; reg < 4; reg++) {
            const int grow = grow0 + quad*4 + reg;
            P.Opart[((size_t)mc*ROWS + grow)*128 + 16*j + L] = O[j][reg];
        }
    if (L == 0) {
        #pragma unroll
        for (int reg = 0; reg < 4; reg++)
            P.Lpart[(size_t)mc*ROWS + grow0 + quad*4 + reg] = ls[reg];
    }
}

// ===================== Phase C: combine partials -> H planes + SQ ============
__global__ __launch_bounds__(NTHR, 2) void k_pC(Params P)
{
    const int lane = threadIdx.x & 63, w = threadIdx.x >> 6;
    const int row = blockIdx.x * 4 + w;
    float Ls = 0.f, o0 = 0.f, o1 = 0.f;
    #pragma unroll
    for (int p = 0; p < 8; p++) {
        Ls += P.Lpart[(size_t)p*ROWS + row];
        const float* op = P.Opart + ((size_t)p*ROWS + row)*128;
        o0 += op[lane];
        o1 += op[lane + 64];
    }
    const float invl = 1.0f / Ls;
    const float h0 = o0*invl + P.Rbuf[(size_t)row*128 + lane];
    const float h1 = o1*invl + P.Rbuf[(size_t)row*128 + lane + 64];
    ushort hh, ll;
    split2(h0, hh, ll); P.Hh[(size_t)row*128 + lane] = hh;      P.Hl[(size_t)row*128 + lane] = ll;
    split2(h1, hh, ll); P.Hh[(size_t)row*128 + lane + 64] = hh; P.Hl[(size_t)row*128 + lane + 64] = ll;
    float s = h0*h0 + h1*h1;
    #pragma unroll
    for (int off = 1; off < 64; off <<= 1) s += __shfl_xor(s, off);
    if (lane == 0) P.SQ[row] = s;
}

// ===================== Phase D: AB GEMM + dist GEMM (symmetric: 36/64 tiles) =
__global__ __launch_bounds__(NTHR, 2) void k_pD(Params P)
{
    __shared__ ushort SMEM[4*64*LDK];
    ushort (*Ah)[LDK] = (ushort(*)[LDK])(SMEM);
    ushort (*Al)[LDK] = (ushort(*)[LDK])(SMEM + 2560);
    ushort (*Bh)[LDK] = (ushort(*)[LDK])(SMEM + 5120);
    ushort (*Bl)[LDK] = (ushort(*)[LDK])(SMEM + 7680);

    const int tid = threadIdx.x, lane = tid & 63, w = tid >> 6;
    const int wr = (w >> 1) * 32, wc = (w & 1) * 32;
    const int m = lane & 15, q4 = (lane >> 4) * 4;
    const int job = blockIdx.x;

    f32x4 acc[2][2];
    #pragma unroll
    for (int i = 0; i < 2; i++)
        #pragma unroll
        for (int j = 0; j < 2; j++) acc[i][j] = (f32x4){0.f,0.f,0.f,0.f};

    if (job < 1024) {        // ---- AB (pure-copy staging from Wct planes) ----
        const int ct = job >> 7, br0 = (job & 127) * 64;
        const bool bhalf = ct >= 4;
        const int c0 = (ct & 3) * 64;
        for (int k0 = 0; k0 < HID; k0 += BK) {
            stage_u(Ah, P.Hh + (size_t)br0 * 128 + k0, 128, tid);
            stage_u(Al, P.Hl + (size_t)br0 * 128 + k0, 128, tid);
            stage_u(Bh, P.Wcth + (size_t)(ct*64) * 128 + k0, 128, tid);
            stage_u(Bl, P.Wctl + (size_t)(ct*64) * 128 + k0, 128, tid);
            __syncthreads();
            mma_step64(Ah, Al, Bh, Bl, acc, wr, wc, lane);
            __syncthreads();
        }
        #pragma unroll
        for (int i = 0; i < 2; i++)
            #pragma unroll
            for (int reg = 0; reg < 4; reg++) {
                const int grow = br0 + wr + 16*i + q4 + reg;
                #pragma unroll
                for (int j = 0; j < 2; j++) {
                    const int c = wc + 16*j + m;
                    const float add = bhalf ? 0.0f : P.bc[c0 + c];
                    P.AB[(size_t)grow * 512 + ct*64 + c] = acc[i][j][reg] + add;
                }
            }
    } else {                 // ---- dist: upper-triangle tiles only ----
        const int t = job - 1024;          // 0..575
        const int b = t / 36;
        int rem = t - b * 36, ti = 0;
        while (rem >= 8 - ti) { rem -= 8 - ti; ti++; }
        const int tj = ti + rem;
        const int n0 = ti * 64, m0 = tj * 64;

        for (int k0 = 0; k0 < HID; k0 += BK) {
            stage_u(Ah, P.Hh + (size_t)(b*NN + n0) * 128 + k0, 128, tid);
            stage_u(Al, P.Hl + (size_t)(b*NN + n0) * 128 + k0, 128, tid);
            stage_u(Bh, P.Hh + (size_t)(b*NN + m0) * 128 + k0, 128, tid);
            stage_u(Bl, P.Hl + (size_t)(b*NN + m0) * 128 + k0, 128, tid);
            __syncthreads();
            mma_step64(Ah, Al, Bh, Bl, acc, wr, wc, lane);
            __syncthreads();
        }
        const int gb = b * NN;
        float* Db = P.D + (size_t)b * NN * NN;
        float sqm[2];
        #pragma unroll
        for (int j = 0; j < 2; j++) sqm[j] = P.SQ[gb + m0 + wc + 16*j + m];

        float* fbuf = (float*)SMEM;   // 64x65 fp32; LDS dead after k-loop
        #pragma unroll
        for (int i = 0; i < 2; i++)
            #pragma unroll
            for (int reg = 0; reg < 4; reg++) {
                const int rloc = wr + 16*i + q4 + reg;
                const int n = n0 + rloc;
                const float sqn = P.SQ[gb + n];
                #pragma unroll
                for (int j = 0; j < 2; j++) {
                    const int cloc = wc + 16*j + m;
                    const float val = sqn + sqm[j] - 2.0f * acc[i][j][reg];
                    Db[(size_t)n * NN + m0 + cloc] = val;
                    if (ti != tj) fbuf[rloc*65 + cloc] = val;
                }
            }
        if (ti != tj) {      // mirror tile via LDS transpose, coalesced store
            __syncthreads();
            const int mloc = tid >> 2, cs = (tid & 3) * 16;
            float* dst = Db + (size_t)(m0 + mloc) * NN + n0 + cs;
            #pragma unroll
            for (int tt = 0; tt < 16; tt += 4) {
                float4 q;
                q.x = fbuf[(cs+tt)*65   + mloc];
                q.y = fbuf[(cs+tt+1)*65 + mloc];
                q.z = fbuf[(cs+tt+2)*65 + mloc];
                q.w = fbuf[(cs+tt+3)*65 + mloc];
                *(float4*)(dst + tt) = q;
            }
        }
    }
}

// ===================== Phase E: top-16 (deferred gather) + LN + SELU =========
__global__ __launch_bounds__(NTHR, 2) void k_pE(Params P)
{
    const int lane = threadIdx.x & 63, w = threadIdx.x >> 6;
    const int row = blockIdx.x * 4 + w;
    const int gb0 = row & ~(NN - 1);
    const float* drow = P.D + (size_t)row * NN;
    const float4 dq0 = ((const float4*)drow)[lane];
    const float4 dq1 = ((const float4*)drow)[64 + lane];
    float v[8] = {dq0.x, dq0.y, dq0.z, dq0.w, dq1.x, dq1.y, dq1.z, dq1.w};

    const float lsc0 = P.lns[lane],       lbi0 = P.lnb[lane];
    const float lsc1 = P.lns[lane + 64],  lbi1 = P.lnb[lane + 64];
    const float lsc2 = P.lns[lane + 128], lbi2 = P.lnb[lane + 128];
    const float lsc3 = P.lns[lane + 192], lbi3 = P.lnb[lane + 192];
    const float* arow = P.AB + (size_t)row * 512;
    const float a0 = arow[lane], a1 = arow[lane + 64],
                a2 = arow[lane + 128], a3 = arow[lane + 192];

    // ---- select all 16 indices first ----
    int idx[TOPK];
    #pragma unroll
    for (int it = 0; it < TOPK; it++) {
        float bestv = v[0]; int bestm = 4*lane;
        #pragma unroll
        for (int j = 1; j < 8; j++) {
            const int mm = (j >> 2)*256 + 4*lane + (j & 3);
            if (v[j] < bestv) { bestv = v[j]; bestm = mm; }
        }
        #pragma unroll
        for (int off = 1; off < 64; off <<= 1) {
            const float ov = __shfl_xor(bestv, off);
            const int   om = __shfl_xor(bestm, off);
            if (ov < bestv || (ov == bestv && om < bestm)) { bestv = ov; bestm = om; }
        }
        idx[it] = bestm;
        if (((bestm >> 2) & 63) == lane) {
            const int jj = ((bestm >> 8) << 2) | (bestm & 3);
            #pragma unroll
            for (int j = 0; j < 8; j++) if (j == jj) v[j] = INFINITY;
        }
    }

    // ---- gather all 16 neighbor rows (independent, latency pipelined) ----
    float bm0 = -INFINITY, bm1 = -INFINITY, bm2 = -INFINITY, bm3 = -INFINITY;
    #pragma unroll
    for (int k2 = 0; k2 < TOPK; k2++) {
        const float* brow = P.AB + (size_t)(gb0 + idx[k2]) * 512 + 256;
        bm0 = fmaxf(bm0, brow[lane]);
        bm1 = fmaxf(bm1, brow[lane + 64]);
        bm2 = fmaxf(bm2, brow[lane + 128]);
        bm3 = fmaxf(bm3, brow[lane + 192]);
    }

    float y0 = a0 + bm0, y1 = a1 + bm1, y2 = a2 + bm2, y3 = a3 + bm3;
    float s = y0 + y1 + y2 + y3;
    #pragma unroll
    for (int off = 1; off < 64; off <<= 1) s += __shfl_xor(s, off);
    const float mu = s * (1.0f/256.0f);
    const float d0 = y0 - mu, d1 = y1 - mu, d2 = y2 - mu, d3 = y3 - mu;
    float s2 = d0*d0 + d1*d1 + d2*d2 + d3*d3;
    #pragma unroll
    for (int off = 1; off < 64; off <<= 1) s2 += __shfl_xor(s2, off);
    const float var = s2 * (1.0f/256.0f);
    const float rstd = rsqrtf(var + LN_EPS);

    const float lam = 1.0507009873554805f, alpha = 1.6732632423543772f;
    float* orow = P.out + (size_t)row * FOUT;
    { const float z = d0*rstd*lsc0 + lbi0; orow[lane]       = z > 0.f ? lam*z : lam*alpha*expm1f(z); }
    { const float z = d1*rstd*lsc1 + lbi1; orow[lane + 64]  = z > 0.f ? lam*z : lam*alpha*expm1f(z); }
    { const float z = d2*rstd*lsc2 + lbi2; orow[lane + 128] = z > 0.f ? lam*z : lam*alpha*expm1f(z); }
    { const float z = d3*rstd*lsc3 + lbi3; orow[lane + 192] = z > 0.f ? lam*z : lam*alpha*expm1f(z); }
}

// ---------------------------------------------------------------------------
extern "C" void kernel_launch(void* const* d_in, const int* in_sizes, int n_in,
                              void* d_out, int out_size, void* d_ws, size_t ws_size,
                              hipStream_t stream)
{
    (void)in_sizes; (void)n_in; (void)out_size; (void)ws_size;

    char* cur = (char*)d_ws;
    auto alloc = [&](size_t bytes) { char* p = cur; cur += (bytes + 255) & ~size_t(255); return p; };

    Params P;
    P.X   = (const float*)d_in[0];
    P.Wq  = (const float*)d_in[2];
    P.bq  = (const float*)d_in[3];
    P.Wk  = (const float*)d_in[4];
    P.bk  = (const float*)d_in[5];
    P.Wv  = (const float*)d_in[6];
    P.bv  = (const float*)d_in[7];
    P.Wr  = (const float*)d_in[8];
    P.br  = (const float*)d_in[9];
    P.Wc  = (const float*)d_in[10];
    P.bc  = (const float*)d_in[11];
    P.lns = (const float*)d_in[12];
    P.lnb = (const float*)d_in[13];
    P.out = (float*)d_out;

    P.D     = (float*)alloc((size_t)NB*NN*NN*4);
    P.AB    = (float*)alloc((size_t)ROWS*512*4);
    P.Opart = (float*)alloc((size_t)8*ROWS*128*4);
    P.Lpart = (float*)alloc((size_t)8*ROWS*4);
    P.Rbuf  = (float*)alloc((size_t)ROWS*128*4);
    P.SQ    = (float*)alloc((size_t)ROWS*4);
    P.Yh    = (ushort*)alloc((size_t)ROWS*256*2);
    P.Yl    = (ushort*)alloc((size_t)ROWS*256*2);
    P.Vth   = (ushort*)alloc((size_t)NB*128*512*2);
    P.Vtl   = (ushort*)alloc((size_t)NB*128*512*2);
    P.Hh    = (ushort*)alloc((size_t)ROWS*128*2);
    P.Hl    = (ushort*)alloc((size_t)ROWS*128*2);
    P.Wcth  = (ushort*)alloc((size_t)512*128*2);
    P.Wctl  = (ushort*)alloc((size_t)512*128*2);

    k_pA<<<1032, NTHR, 0, stream>>>(P);
    k_pB<<<1024, NTHR, 0, stream>>>(P);
    k_pC<<<2048, NTHR, 0, stream>>>(P);
    k_pD<<<1600, NTHR, 0, stream>>>(P);
    k_pE<<<2048, NTHR, 0, stream>>>(P);
}

// Round 14
// 179.404 us; speedup vs baseline: 1.0635x; 1.0635x over previous
//
#include <hip/hip_runtime.h>
#include <math.h>

// Problem constants
#define NB   16
#define NN   512
#define FIN  256
#define HID  128
#define FOUT 256
#define TOPK 16
#define ROWS (NB*NN)
#define LN_EPS 1e-5f

#define BK   32
#define LDK  40     // padded LDS row (ushort): 80B stride
#define LDKK 136    // K-tile row stride (ushort): 272B, 16B-aligned, 2-way banks
#define NTHR 256

typedef __attribute__((ext_vector_type(8)))  short  bf16x8;
typedef __attribute__((ext_vector_type(4)))  float  f32x4;
typedef __attribute__((ext_vector_type(8)))  unsigned short u16x8;

#define MFMA3(d, ah, al, bh, bl)                                              \
    d = __builtin_amdgcn_mfma_f32_16x16x32_bf16(ah, bh, d, 0, 0, 0);          \
    d = __builtin_amdgcn_mfma_f32_16x16x32_bf16(ah, bl, d, 0, 0, 0);          \
    d = __builtin_amdgcn_mfma_f32_16x16x32_bf16(al, bh, d, 0, 0, 0);

__device__ __forceinline__ ushort f2bf_rn(float x) {
    uint u = __float_as_uint(x);
    u += 0x7fff + ((u >> 16) & 1);
    return (ushort)(u >> 16);
}
__device__ __forceinline__ float bf2f(ushort h) {
    return __uint_as_float(((uint)h) << 16);
}
__device__ __forceinline__ void split2(float x, ushort& hi, ushort& lo) {
    hi = f2bf_rn(x);
    lo = f2bf_rn(x - bf2f(hi));
}

// stage 64 rows x 32 k from fp32 row-major source (contiguous k), split on fly
__device__ __forceinline__ void stage_rows64f(ushort (*Dh)[LDK], ushort (*Dl)[LDK],
                                              const float* __restrict__ src,
                                              int rstride, int tid)
{
    const int r = tid >> 2, seg = (tid & 3) * 8;
    const float* p = src + (size_t)r * rstride + seg;
    #pragma unroll
    for (int i = 0; i < 2; i++) {
        const float4 q = *(const float4*)(p + 4*i);
        ushort h0,l0,h1,l1,h2,l2,h3,l3;
        split2(q.x,h0,l0); split2(q.y,h1,l1);
        split2(q.z,h2,l2); split2(q.w,h3,l3);
        *(ushort4*)&Dh[r][seg + 4*i] = make_ushort4(h0,h1,h2,h3);
        *(ushort4*)&Dl[r][seg + 4*i] = make_ushort4(l0,l1,l2,l3);
    }
}

// stage transposed from fp32 [k][n] source (ld = ldn), write [n][k], n=64 wide
__device__ __forceinline__ void stage_cols64f(ushort (*Dh)[LDK], ushort (*Dl)[LDK],
                                              const float* __restrict__ src,
                                              int ldn, int tid)
{
    const int n = tid & 63, kh = (tid >> 6) * 8;
    const float* p = src + (size_t)kh * ldn + n;
    ushort hh[8], ll[8];
    #pragma unroll
    for (int i = 0; i < 8; i++) split2(p[(size_t)i * ldn], hh[i], ll[i]);
    *(ushort4*)&Dh[n][kh]     = make_ushort4(hh[0],hh[1],hh[2],hh[3]);
    *(ushort4*)&Dh[n][kh + 4] = make_ushort4(hh[4],hh[5],hh[6],hh[7]);
    *(ushort4*)&Dl[n][kh]     = make_ushort4(ll[0],ll[1],ll[2],ll[3]);
    *(ushort4*)&Dl[n][kh + 4] = make_ushort4(ll[4],ll[5],ll[6],ll[7]);
}

// stage 64 rows x 32 k of a pre-split ushort plane into LDS (pure copy)
__device__ __forceinline__ void stage_u(ushort (*Ds)[LDK], const ushort* __restrict__ src,
                                        int rstride, int tid)
{
    const int r = tid >> 2, seg = (tid & 3) * 8;
    *(u16x8*)&Ds[r][seg] = *(const u16x8*)(src + (size_t)r * rstride + seg);
}

__device__ __forceinline__ void mma_step64(const ushort (*Ah)[LDK], const ushort (*Al)[LDK],
                                           const ushort (*Bh)[LDK], const ushort (*Bl)[LDK],
                                           f32x4 acc[2][2], int wr, int wc, int lane)
{
    const int q8 = (lane >> 4) * 8, m = lane & 15;
    bf16x8 ah[2], al[2], bh[2], bl[2];
    #pragma unroll
    for (int i = 0; i < 2; i++) {
        ah[i] = *(const bf16x8*)&Ah[wr + 16*i + m][q8];
        al[i] = *(const bf16x8*)&Al[wr + 16*i + m][q8];
        bh[i] = *(const bf16x8*)&Bh[wc + 16*i + m][q8];
        bl[i] = *(const bf16x8*)&Bl[wc + 16*i + m][q8];
    }
    #pragma unroll
    for (int i = 0; i < 2; i++)
        #pragma unroll
        for (int j = 0; j < 2; j++) {
            MFMA3(acc[i][j], ah[i], al[i], bh[j], bl[j]);
        }
}

struct Params {
    const float *X, *Wq, *bq, *Wk, *bk, *Wv, *bv, *Wr, *br, *Wc, *bc, *lns, *lnb;
    float *out;
    float *Rbuf, *SQ, *AB, *D, *Opart, *Lpart;
    ushort *Yh, *Yl, *Vth, *Vtl, *Hh, *Hl, *Wcth, *Wctl;
};

// ===================== Phase A: projection (+ Wct prep in blocks >=1024) =====
__global__ __launch_bounds__(NTHR, 2) void k_pA(Params P)
{
    __shared__ ushort SMEM[4*64*LDK];

    const int tid = threadIdx.x;

    if (blockIdx.x >= 1024) {            // ---- Wct prep ----
        float (*fb)[65] = (float(*)[65])SMEM;
        const int n0 = (blockIdx.x - 1024) * 64;
        const bool ahalf = n0 < 256;
        const int cbase = n0 & 255;
        for (int kt = 0; kt < 2; kt++) {
            const int k0 = kt * 64;
            __syncthreads();
            {
                const int kk = tid >> 2, cs = (tid & 3) * 16;
                #pragma unroll
                for (int t = 0; t < 16; t++) {
                    const float bot = P.Wc[(size_t)(HID + k0 + kk)*FOUT + cbase + cs + t];
                    float val = bot;
                    if (ahalf) val = P.Wc[(size_t)(k0 + kk)*FOUT + cbase + cs + t] - bot;
                    fb[kk][cs+t] = val;
                }
            }
            __syncthreads();
            {
                const int c = tid >> 2, ks = (tid & 3) * 16;
                u16x8 vh0, vh1, vl0, vl1;
                #pragma unroll
                for (int t = 0; t < 8; t++) {
                    ushort hh, ll;
                    split2(fb[ks+t][c], hh, ll);   vh0[t]=hh; vl0[t]=ll;
                    split2(fb[ks+8+t][c], hh, ll); vh1[t]=hh; vl1[t]=ll;
                }
                *(u16x8*)&P.Wcth[(size_t)(n0+c)*128 + k0 + ks]     = vh0;
                *(u16x8*)&P.Wcth[(size_t)(n0+c)*128 + k0 + ks + 8] = vh1;
                *(u16x8*)&P.Wctl[(size_t)(n0+c)*128 + k0 + ks]     = vl0;
                *(u16x8*)&P.Wctl[(size_t)(n0+c)*128 + k0 + ks + 8] = vl1;
            }
        }
        return;
    }

    ushort (*Ah)[LDK] = (ushort(*)[LDK])(SMEM);
    ushort (*Al)[LDK] = (ushort(*)[LDK])(SMEM + 2560);
    ushort (*Bh)[LDK] = (ushort(*)[LDK])(SMEM + 5120);
    ushort (*Bl)[LDK] = (ushort(*)[LDK])(SMEM + 7680);
    float* fbuf = (float*)SMEM;

    const int lane = tid & 63, w = tid >> 6;
    const int wr = (w >> 1) * 32, wc = (w & 1) * 32;
    const int m = lane & 15, q4 = (lane >> 4) * 4;

    const int job = blockIdx.x;
    const int ct = job >> 7, br0 = (job & 127) * 64;
    const int widx = ct >> 1, ch = (ct & 1) * 64;
    const float* W    = widx==0 ? P.Wq : widx==1 ? P.Wk : widx==2 ? P.Wv : P.Wr;
    const float* bias = widx==0 ? P.bq : widx==1 ? P.bk : widx==2 ? P.bv : P.br;

    f32x4 acc[2][2];
    #pragma unroll
    for (int i = 0; i < 2; i++)
        #pragma unroll
        for (int j = 0; j < 2; j++) acc[i][j] = (f32x4){0.f,0.f,0.f,0.f};

    for (int k0 = 0; k0 < FIN; k0 += BK) {
        stage_rows64f(Ah, Al, P.X + (size_t)br0 * FIN + k0, FIN, tid);
        stage_cols64f(Bh, Bl, W + (size_t)k0 * HID + ch, HID, tid);
        __syncthreads();
        mma_step64(Ah, Al, Bh, Bl, acc, wr, wc, lane);
        __syncthreads();
    }
    #pragma unroll
    for (int i = 0; i < 2; i++)
        #pragma unroll
        for (int reg = 0; reg < 4; reg++) {
            const int r = wr + 16*i + q4 + reg;
            #pragma unroll
            for (int j = 0; j < 2; j++) {
                const int c = wc + 16*j + m;
                fbuf[r*65 + c] = acc[i][j][reg] + bias[ch + c];
            }
        }
    __syncthreads();

    if (ct < 4) {            // q|k planes, row-major [8192][256]; q pre-scaled
        const float qsc = (ct < 2) ? 0.08838834764831845f : 1.0f;
        const int r = tid >> 2, cs = (tid & 3) * 16;
        u16x8 vh0, vh1, vl0, vl1;
        #pragma unroll
        for (int t = 0; t < 8; t++) {
            ushort hh, ll;
            split2(fbuf[r*65 + cs + t] * qsc, hh, ll);     vh0[t]=hh; vl0[t]=ll;
            split2(fbuf[r*65 + cs + 8 + t] * qsc, hh, ll); vh1[t]=hh; vl1[t]=ll;
        }
        const size_t o = (size_t)(br0 + r) * 256 + ct*64 + cs;
        *(u16x8*)&P.Yh[o]   = vh0; *(u16x8*)&P.Yh[o+8] = vh1;
        *(u16x8*)&P.Yl[o]   = vl0; *(u16x8*)&P.Yl[o+8] = vl1;
    } else if (ct < 6) {     // V transposed planes [b][c=128][n=512]
        const int cl = tid >> 2, rs = (tid & 3) * 16;
        const int b = br0 >> 9, nb = br0 & 511;
        const int cglob = (ct - 4) * 64 + cl;
        u16x8 vh0, vh1, vl0, vl1;
        #pragma unroll
        for (int t = 0; t < 8; t++) {
            ushort hh, ll;
            split2(fbuf[(rs+t)*65 + cl], hh, ll);   vh0[t]=hh; vl0[t]=ll;
            split2(fbuf[(rs+8+t)*65 + cl], hh, ll); vh1[t]=hh; vl1[t]=ll;
        }
        const size_t o = ((size_t)b*128 + cglob) * 512 + nb + rs;
        *(u16x8*)&P.Vth[o]   = vh0; *(u16x8*)&P.Vth[o+8] = vh1;
        *(u16x8*)&P.Vtl[o]   = vl0; *(u16x8*)&P.Vtl[o+8] = vl1;
    } else {                 // R fp32 [8192][128]
        const int r = tid >> 2, cs = (tid & 3) * 16;
        float* dst = P.Rbuf + (size_t)(br0 + r) * 128 + (ct - 6)*64 + cs;
        #pragma unroll
        for (int t = 0; t < 16; t += 4) {
            float4 q;
            q.x = fbuf[r*65+cs+t];   q.y = fbuf[r*65+cs+t+1];
            q.z = fbuf[r*65+cs+t+2]; q.w = fbuf[r*65+cs+t+3];
            *(float4*)(dst + t) = q;
        }
    }
}

// ===================== Phase B: attention partials — single barrier ==========
// K-tile (64 m x 128 k, split) staged once into dedicated LDS (shared across
// waves); P buffers wave-private. Exactly one __syncthreads.
__global__ __launch_bounds__(NTHR, 2) void k_pB(Params P)
{
    __shared__ ushort SMEM[2*64*LDKK + 4*64*LDK];   // 55296 B
    ushort (*Kh)[LDKK] = (ushort(*)[LDKK])(SMEM);
    ushort (*Kl)[LDKK] = (ushort(*)[LDKK])(SMEM + 64*LDKK);
    ushort* PB = SMEM + 2*64*LDKK;
    ushort (*P0h)[LDK] = (ushort(*)[LDK])(PB);
    ushort (*P0l)[LDK] = (ushort(*)[LDK])(PB + 2560);
    ushort (*P1h)[LDK] = (ushort(*)[LDK])(PB + 5120);
    ushort (*P1l)[LDK] = (ushort(*)[LDK])(PB + 7680);

    const int tid = threadIdx.x, lane = tid & 63, w = tid >> 6;
    const int L = lane & 15, quad = lane >> 4;

    const int job = blockIdx.x;
    const int b = job >> 6, rest = job & 63;
    const int n0 = (rest >> 3) * 64, mc = rest & 7, m0 = mc * 64;
    const int grow0 = b*NN + n0 + w*16;

    // stage full K-tile: thread -> row tid>>2, 32-elem seg (tid&3)*32
    {
        const int r = tid >> 2, sg = (tid & 3) * 32;
        const size_t kbase = (size_t)(b*NN + m0 + r) * 256 + 128 + sg;
        #pragma unroll
        for (int i = 0; i < 4; i++) {
            *(u16x8*)&Kh[r][sg + 8*i] = *(const u16x8*)(P.Yh + kbase + 8*i);
            *(u16x8*)&Kl[r][sg + 8*i] = *(const u16x8*)(P.Yl + kbase + 8*i);
        }
    }

    bf16x8 qh[4], ql[4];
    #pragma unroll
    for (int s = 0; s < 4; s++) {
        const size_t qo = (size_t)(grow0 + L) * 256 + s*32 + quad*8;
        qh[s] = *(const bf16x8*)(P.Yh + qo);
        ql[s] = *(const bf16x8*)(P.Yl + qo);
    }

    __syncthreads();   // the only barrier in this kernel

    f32x4 Sf[4];
    #pragma unroll
    for (int j = 0; j < 4; j++) Sf[j] = (f32x4){0.f,0.f,0.f,0.f};
    #pragma unroll
    for (int s = 0; s < 4; s++)
        #pragma unroll
        for (int j = 0; j < 4; j++) {
            bf16x8 kh = *(const bf16x8*)&Kh[16*j + L][s*32 + quad*8];
            bf16x8 kl = *(const bf16x8*)&Kl[16*j + L][s*32 + quad*8];
            MFMA3(Sf[j], qh[s], ql[s], kh, kl);
        }

    // exp (no max shift: |s| small), stash P into wave-private LDS rows
    float ls[4] = {0.f, 0.f, 0.f, 0.f};
    #pragma unroll
    for (int j = 0; j < 4; j++)
        #pragma unroll
        for (int r = 0; r < 4; r++) {
            const float p = __expf(Sf[j][r]);
            ls[r] += p;
            const int row = w*16 + quad*4 + r, cc = (16*j + L) & 31;
            ushort hh, ll; split2(p, hh, ll);
            if (j < 2) { P0h[row][cc] = hh; P0l[row][cc] = ll; }
            else       { P1h[row][cc] = hh; P1l[row][cc] = ll; }
        }
    #pragma unroll
    for (int r = 0; r < 4; r++) {
        float v = ls[r];
        v += __shfl_xor(v, 1); v += __shfl_xor(v, 2);
        v += __shfl_xor(v, 4); v += __shfl_xor(v, 8);
        ls[r] = v;
    }

    // O = P @ V^T (V frags direct from global; P rows wave-private)
    f32x4 O[8];
    #pragma unroll
    for (int j = 0; j < 8; j++) O[j] = (f32x4){0.f,0.f,0.f,0.f};
    #pragma unroll
    for (int s2 = 0; s2 < 2; s2++) {
        bf16x8 ph = s2 ? *(const bf16x8*)&P1h[w*16 + L][quad*8]
                       : *(const bf16x8*)&P0h[w*16 + L][quad*8];
        bf16x8 pl = s2 ? *(const bf16x8*)&P1l[w*16 + L][quad*8]
                       : *(const bf16x8*)&P0l[w*16 + L][quad*8];
        #pragma unroll
        for (int j = 0; j < 8; j++) {
            const size_t vo = ((size_t)(b*128 + 16*j + L)) * 512 + m0 + s2*32 + quad*8;
            bf16x8 vh = *(const bf16x8*)(P.Vth + vo);
            bf16x8 vl = *(const bf16x8*)(P.Vtl + vo);
            MFMA3(O[j], ph, pl, vh, vl);
        }
    }

    #pragma unroll
    for (int j = 0; j < 8; j++)
        #pragma unroll
        for (int reg = 0; reg < 4; reg++) {
            const int grow = grow0 + quad*4 + reg;
            P.Opart[((size_t)mc*ROWS + grow)*128 + 16*j + L] = O[j][reg];
        }
    if (L == 0) {
        #pragma unroll
        for (int reg = 0; reg < 4; reg++)
            P.Lpart[(size_t)mc*ROWS + grow0 + quad*4 + reg] = ls[reg];
    }
}

// ===================== Phase C: combine partials -> H planes + SQ ============
__global__ __launch_bounds__(NTHR, 2) void k_pC(Params P)
{
    const int lane = threadIdx.x & 63, w = threadIdx.x >> 6;
    const int row = blockIdx.x * 4 + w;
    float Ls = 0.f, o0 = 0.f, o1 = 0.f;
    #pragma unroll
    for (int p = 0; p < 8; p++) {
        Ls += P.Lpart[(size_t)p*ROWS + row];
        const float* op = P.Opart + ((size_t)p*ROWS + row)*128;
        o0 += op[lane];
        o1 += op[lane + 64];
    }
    const float invl = 1.0f / Ls;
    const float h0 = o0*invl + P.Rbuf[(size_t)row*128 + lane];
    const float h1 = o1*invl + P.Rbuf[(size_t)row*128 + lane + 64];
    ushort hh, ll;
    split2(h0, hh, ll); P.Hh[(size_t)row*128 + lane] = hh;      P.Hl[(size_t)row*128 + lane] = ll;
    split2(h1, hh, ll); P.Hh[(size_t)row*128 + lane + 64] = hh; P.Hl[(size_t)row*128 + lane + 64] = ll;
    float s = h0*h0 + h1*h1;
    #pragma unroll
    for (int off = 1; off < 64; off <<= 1) s += __shfl_xor(s, off);
    if (lane == 0) P.SQ[row] = s;
}

// ===================== Phase D: AB GEMM + dist GEMM (symmetric: 36/64 tiles) =
__global__ __launch_bounds__(NTHR, 2) void k_pD(Params P)
{
    __shared__ ushort SMEM[4*64*LDK];
    ushort (*Ah)[LDK] = (ushort(*)[LDK])(SMEM);
    ushort (*Al)[LDK] = (ushort(*)[LDK])(SMEM + 2560);
    ushort (*Bh)[LDK] = (ushort(*)[LDK])(SMEM + 5120);
    ushort (*Bl)[LDK] = (ushort(*)[LDK])(SMEM + 7680);

    const int tid = threadIdx.x, lane = tid & 63, w = tid >> 6;
    const int wr = (w >> 1) * 32, wc = (w & 1) * 32;
    const int m = lane & 15, q4 = (lane >> 4) * 4;
    const int job = blockIdx.x;

    f32x4 acc[2][2];
    #pragma unroll
    for (int i = 0; i < 2; i++)
        #pragma unroll
        for (int j = 0; j < 2; j++) acc[i][j] = (f32x4){0.f,0.f,0.f,0.f};

    if (job < 1024) {        // ---- AB (pure-copy staging from Wct planes) ----
        const int ct = job >> 7, br0 = (job & 127) * 64;
        const bool bhalf = ct >= 4;
        const int c0 = (ct & 3) * 64;
        for (int k0 = 0; k0 < HID; k0 += BK) {
            stage_u(Ah, P.Hh + (size_t)br0 * 128 + k0, 128, tid);
            stage_u(Al, P.Hl + (size_t)br0 * 128 + k0, 128, tid);
            stage_u(Bh, P.Wcth + (size_t)(ct*64) * 128 + k0, 128, tid);
            stage_u(Bl, P.Wctl + (size_t)(ct*64) * 128 + k0, 128, tid);
            __syncthreads();
            mma_step64(Ah, Al, Bh, Bl, acc, wr, wc, lane);
            __syncthreads();
        }
        #pragma unroll
        for (int i = 0; i < 2; i++)
            #pragma unroll
            for (int reg = 0; reg < 4; reg++) {
                const int grow = br0 + wr + 16*i + q4 + reg;
                #pragma unroll
                for (int j = 0; j < 2; j++) {
                    const int c = wc + 16*j + m;
                    const float add = bhalf ? 0.0f : P.bc[c0 + c];
                    P.AB[(size_t)grow * 512 + ct*64 + c] = acc[i][j][reg] + add;
                }
            }
    } else {                 // ---- dist: upper-triangle tiles only ----
        const int t = job - 1024;          // 0..575
        const int b = t / 36;
        int rem = t - b * 36, ti = 0;
        while (rem >= 8 - ti) { rem -= 8 - ti; ti++; }
        const int tj = ti + rem;
        const int n0 = ti * 64, m0 = tj * 64;

        for (int k0 = 0; k0 < HID; k0 += BK) {
            stage_u(Ah, P.Hh + (size_t)(b*NN + n0) * 128 + k0, 128, tid);
            stage_u(Al, P.Hl + (size_t)(b*NN + n0) * 128 + k0, 128, tid);
            stage_u(Bh, P.Hh + (size_t)(b*NN + m0) * 128 + k0, 128, tid);
            stage_u(Bl, P.Hl + (size_t)(b*NN + m0) * 128 + k0, 128, tid);
            __syncthreads();
            mma_step64(Ah, Al, Bh, Bl, acc, wr, wc, lane);
            __syncthreads();
        }
        const int gb = b * NN;
        float* Db = P.D + (size_t)b * NN * NN;
        float sqm[2];
        #pragma unroll
        for (int j = 0; j < 2; j++) sqm[j] = P.SQ[gb + m0 + wc + 16*j + m];

        float* fbuf = (float*)SMEM;   // 64x65 fp32; LDS dead after k-loop
        #pragma unroll
        for (int i = 0; i < 2; i++)
            #pragma unroll
            for (int reg = 0; reg < 4; reg++) {
                const int rloc = wr + 16*i + q4 + reg;
                const int n = n0 + rloc;
                const float sqn = P.SQ[gb + n];
                #pragma unroll
                for (int j = 0; j < 2; j++) {
                    const int cloc = wc + 16*j + m;
                    const float val = sqn + sqm[j] - 2.0f * acc[i][j][reg];
                    Db[(size_t)n * NN + m0 + cloc] = val;
                    if (ti != tj) fbuf[rloc*65 + cloc] = val;
                }
            }
        if (ti != tj) {      // mirror tile via LDS transpose, coalesced store
            __syncthreads();
            const int mloc = tid >> 2, cs = (tid & 3) * 16;
            float* dst = Db + (size_t)(m0 + mloc) * NN + n0 + cs;
            #pragma unroll
            for (int tt = 0; tt < 16; tt += 4) {
                float4 q;
                q.x = fbuf[(cs+tt)*65   + mloc];
                q.y = fbuf[(cs+tt+1)*65 + mloc];
                q.z = fbuf[(cs+tt+2)*65 + mloc];
                q.w = fbuf[(cs+tt+3)*65 + mloc];
                *(float4*)(dst + tt) = q;
            }
        }
    }
}

// ===================== Phase E: top-16 (deferred gather) + LN + SELU =========
__global__ __launch_bounds__(NTHR, 2) void k_pE(Params P)
{
    const int lane = threadIdx.x & 63, w = threadIdx.x >> 6;
    const int row = blockIdx.x * 4 + w;
    const int gb0 = row & ~(NN - 1);
    const float* drow = P.D + (size_t)row * NN;
    const float4 dq0 = ((const float4*)drow)[lane];
    const float4 dq1 = ((const float4*)drow)[64 + lane];
    float v[8] = {dq0.x, dq0.y, dq0.z, dq0.w, dq1.x, dq1.y, dq1.z, dq1.w};

    const float lsc0 = P.lns[lane],       lbi0 = P.lnb[lane];
    const float lsc1 = P.lns[lane + 64],  lbi1 = P.lnb[lane + 64];
    const float lsc2 = P.lns[lane + 128], lbi2 = P.lnb[lane + 128];
    const float lsc3 = P.lns[lane + 192], lbi3 = P.lnb[lane + 192];
    const float* arow = P.AB + (size_t)row * 512;
    const float a0 = arow[lane], a1 = arow[lane + 64],
                a2 = arow[lane + 128], a3 = arow[lane + 192];

    // ---- select all 16 indices first ----
    int idx[TOPK];
    #pragma unroll
    for (int it = 0; it < TOPK; it++) {
        float bestv = v[0]; int bestm = 4*lane;
        #pragma unroll
        for (int j = 1; j < 8; j++) {
            const int mm = (j >> 2)*256 + 4*lane + (j & 3);
            if (v[j] < bestv) { bestv = v[j]; bestm = mm; }
        }
        #pragma unroll
        for (int off = 1; off < 64; off <<= 1) {
            const float ov = __shfl_xor(bestv, off);
            const int   om = __shfl_xor(bestm, off);
            if (ov < bestv || (ov == bestv && om < bestm)) { bestv = ov; bestm = om; }
        }
        idx[it] = bestm;
        if (((bestm >> 2) & 63) == lane) {
            const int jj = ((bestm >> 8) << 2) | (bestm & 3);
            #pragma unroll
            for (int j = 0; j < 8; j++) if (j == jj) v[j] = INFINITY;
        }
    }

    // ---- gather all 16 neighbor rows (independent, latency pipelined) ----
    float bm0 = -INFINITY, bm1 = -INFINITY, bm2 = -INFINITY, bm3 = -INFINITY;
    #pragma unroll
    for (int k2 = 0; k2 < TOPK; k2++) {
        const float* brow = P.AB + (size_t)(gb0 + idx[k2]) * 512 + 256;
        bm0 = fmaxf(bm0, brow[lane]);
        bm1 = fmaxf(bm1, brow[lane + 64]);
        bm2 = fmaxf(bm2, brow[lane + 128]);
        bm3 = fmaxf(bm3, brow[lane + 192]);
    }

    float y0 = a0 + bm0, y1 = a1 + bm1, y2 = a2 + bm2, y3 = a3 + bm3;
    float s = y0 + y1 + y2 + y3;
    #pragma unroll
    for (int off = 1; off < 64; off <<= 1) s += __shfl_xor(s, off);
    const float mu = s * (1.0f/256.0f);
    const float d0 = y0 - mu, d1 = y1 - mu, d2 = y2 - mu, d3 = y3 - mu;
    float s2 = d0*d0 + d1*d1 + d2*d2 + d3*d3;
    #pragma unroll
    for (int off = 1; off < 64; off <<= 1) s2 += __shfl_xor(s2, off);
    const float var = s2 * (1.0f/256.0f);
    const float rstd = rsqrtf(var + LN_EPS);

    const float lam = 1.0507009873554805f, alpha = 1.6732632423543772f;
    float* orow = P.out + (size_t)row * FOUT;
    { const float z = d0*rstd*lsc0 + lbi0; orow[lane]       = z > 0.f ? lam*z : lam*alpha*expm1f(z); }
    { const float z = d1*rstd*lsc1 + lbi1; orow[lane + 64]  = z > 0.f ? lam*z : lam*alpha*expm1f(z); }
    { const float z = d2*rstd*lsc2 + lbi2; orow[lane + 128] = z > 0.f ? lam*z : lam*alpha*expm1f(z); }
    { const float z = d3*rstd*lsc3 + lbi3; orow[lane + 192] = z > 0.f ? lam*z : lam*alpha*expm1f(z); }
}

// ---------------------------------------------------------------------------
extern "C" void kernel_launch(void* const* d_in, const int* in_sizes, int n_in,
                              void* d_out, int out_size, void* d_ws, size_t ws_size,
                              hipStream_t stream)
{
    (void)in_sizes; (void)n_in; (void)out_size; (void)ws_size;

    char* cur = (char*)d_ws;
    auto alloc = [&](size_t bytes) { char* p = cur; cur += (bytes + 255) & ~size_t(255); return p; };

    Params P;
    P.X   = (const float*)d_in[0];
    P.Wq  = (const float*)d_in[2];
    P.bq  = (const float*)d_in[3];
    P.Wk  = (const float*)d_in[4];
    P.bk  = (const float*)d_in[5];
    P.Wv  = (const float*)d_in[6];
    P.bv  = (const float*)d_in[7];
    P.Wr  = (const float*)d_in[8];
    P.br  = (const float*)d_in[9];
    P.Wc  = (const float*)d_in[10];
    P.bc  = (const float*)d_in[11];
    P.lns = (const float*)d_in[12];
    P.lnb = (const float*)d_in[13];
    P.out = (float*)d_out;

    P.D     = (float*)alloc((size_t)NB*NN*NN*4);
    P.AB    = (float*)alloc((size_t)ROWS*512*4);
    P.Opart = (float*)alloc((size_t)8*ROWS*128*4);
    P.Lpart = (float*)alloc((size_t)8*ROWS*4);
    P.Rbuf  = (float*)alloc((size_t)ROWS*128*4);
    P.SQ    = (float*)alloc((size_t)ROWS*4);
    P.Yh    = (ushort*)alloc((size_t)ROWS*256*2);
    P.Yl    = (ushort*)alloc((size_t)ROWS*256*2);
    P.Vth   = (ushort*)alloc((size_t)NB*128*512*2);
    P.Vtl   = (ushort*)alloc((size_t)NB*128*512*2);
    P.Hh    = (ushort*)alloc((size_t)ROWS*128*2);
    P.Hl    = (ushort*)alloc((size_t)ROWS*128*2);
    P.Wcth  = (ushort*)alloc((size_t)512*128*2);
    P.Wctl  = (ushort*)alloc((size_t)512*128*2);

    k_pA<<<1032, NTHR, 0, stream>>>(P);
    k_pB<<<1024, NTHR, 0, stream>>>(P);
    k_pC<<<2048, NTHR, 0, stream>>>(P);
    k_pD<<<1600, NTHR, 0, stream>>>(P);
    k_pE<<<2048, NTHR, 0, stream>>>(P);
}